// Round 7
// baseline (98.444 us; speedup 1.0000x reference)
//
#include <hip/hip_runtime.h>
#include <stdint.h>

// Bitwise reproducibility vs the numpy reference: forbid a*b+c fusion so every
// mul/add rounds exactly like the ref (keep-decision booleans must not flip).
#pragma clang fp contract(off)

typedef unsigned long long u64;
typedef unsigned int u32;
typedef unsigned short u16;

namespace {
constexpr int BB = 4;
constexpr int NN = 4096;
constexpr int CC = 64;
constexpr int BN = BB * NN;
constexpr float TARGET = 560.0f;
constexpr float MIN_BOX = 5.0f;
constexpr float IOU_THR = 0.2f;
constexpr float CONF_THR = 0.001f;
constexpr float BOX_CONF_THR = 0.01f;
constexpr float MAX_WH = 4096.0f;
constexpr int MAXB = 1024;   // k3 compact-list cap; data has ~64 +/- 8 per class
}

__device__ __forceinline__ void zero_row(float* __restrict__ out, int p) {
    float2* o2 = (float2*)(out + (size_t)p * 6);   // p*24B is 8B-aligned
    float2 z; z.x = 0.0f; z.y = 0.0f;
    o2[0] = z; o2[1] = z; o2[2] = z;
}

__device__ __forceinline__ void emit_row(float* __restrict__ out, int p,
                                         float4 bc, float cf, float cls) {
    float2* o2 = (float2*)(out + (size_t)p * 6);
    float2 aa; aa.x = bc.x; aa.y = bc.y;
    float2 cc; cc.x = bc.z; cc.y = bc.w;
    float2 ee; ee.x = cf;   ee.y = cls;
    o2[0] = aa; o2[1] = cc; o2[2] = ee;
}

// clip to [0,TARGET] with the ref's exact op order
__device__ __forceinline__ float4 clip_box(float4 bx) {
    float4 r;
    r.x = fminf(fmaxf(bx.x, 0.0f), TARGET);
    r.y = fminf(fmaxf(bx.y, 0.0f), TARGET);
    r.z = fminf(fmaxf(bx.z, 0.0f), TARGET);
    r.w = fminf(fmaxf(bx.w, 0.0f), TARGET);
    return r;
}

// conf of a VALID element is exactly recoverable from its key's score field:
// valid => sk = best >= 0 => fb sign clear => mm = fb | 0x80000000.
__device__ __forceinline__ float conf_of(u64 key) {
    return __uint_as_float(((u32)(key >> 12)) & 0x7FFFFFFFu);
}

// IoU(i,j) > thr with the ref's exact op order (offset boxes, precomputed areas,
// inter/(ai+aj-inter+1e-9) with IEEE division).
__device__ __forceinline__ bool iou_gt(float4 bi, float ai, float4 bj, float aj) {
    float ltx = fmaxf(bi.x, bj.x);
    float lty = fmaxf(bi.y, bj.y);
    float rbx = fminf(bi.z, bj.z);
    float rby = fminf(bi.w, bj.w);
    float ww = fmaxf(rbx - ltx, 0.0f);
    float hh = fmaxf(rby - lty, 0.0f);
    float inter = ww * hh;
    float iou = inter / (ai + aj - inter + 1e-9f);
    return iou > IOU_THR;
}

// ---------------- k1: conf=max_c(cls*score), argmax, valid, 44-bit key
// (sign-mapped score <<12 | reversed idx => embedded index tie-break, 1 u64
// compare in k2), zero the rank buffer, and build per-(batch,class) validity
// bitmasks via wave ballots (no atomics, no pre-zeroed state). Valid keys
// (>= 2^43) all exceed invalid keys => valid ranks are exactly [0,kv) and
// invalid rows are exactly [kv,4096) -- k3 exploits both. 4 lanes per row;
// block = 64 rows = one mask group. Boxes are NOT staged: k3 re-clips raw input.
__global__ __launch_bounds__(256) void k1_score(const float* __restrict__ boxes,
                                                const float* __restrict__ box_scores,
                                                const float* __restrict__ cls_preds,
                                                u64* __restrict__ key64,
                                                int* __restrict__ rank,
                                                u64* __restrict__ clsmask,
                                                int* __restrict__ kvb) {
    __shared__ u32 cvs[64];                           // per-row packed (cls | valid<<8)
    int r = (blockIdx.x << 6) + (threadIdx.x >> 2);   // 64 rows/block
    int sub = threadIdx.x & 3;
    float bs = box_scores[r];
    const float4* cp = (const float4*)(cls_preds + ((size_t)r << 6) + (sub << 4));
    float best = -1.0f;   // products >= 0, so first element always beats init
    int bestc = sub << 4;
#pragma unroll
    for (int q = 0; q < 4; ++q) {
        float4 v = cp[q];
        float p0 = v.x * bs, p1 = v.y * bs, p2 = v.z * bs, p3 = v.w * bs;
        int cb = (sub << 4) + (q << 2);
        // strict > preserves numpy first-occurrence argmax within a lane
        if (p0 > best) { best = p0; bestc = cb + 0; }
        if (p1 > best) { best = p1; bestc = cb + 1; }
        if (p2 > best) { best = p2; bestc = cb + 2; }
        if (p3 > best) { best = p3; bestc = cb + 3; }
    }
    // quad merge; exact-tie -> smaller class index == first occurrence
#pragma unroll
    for (int d2 = 1; d2 < 4; d2 <<= 1) {
        float ob = __shfl_xor(best, d2);
        int oc = __shfl_xor(bestc, d2);
        if (ob > best || (ob == best && oc < bestc)) { best = ob; bestc = oc; }
    }
    if (sub == 0) {
        float4 bc4 = clip_box(((const float4*)boxes)[r]);
        float w = bc4.z - bc4.x, h = bc4.w - bc4.y;
        bool valid = (bs > BOX_CONF_THR) && (w > MIN_BOX) && (h > MIN_BOX) && (best > CONF_THR);
        float sk = valid ? best : -1.0f;
        // monotonic float->uint map; unique key: ties rank smaller original index
        // first => stable descending sort by score.
        unsigned fb = __float_as_uint(sk);
        unsigned mm = (fb & 0x80000000u) ? ~fb : (fb | 0x80000000u);
        int i = r & (NN - 1);
        key64[r] = ((u64)mm << 12) | (u64)(NN - 1 - i);
        rank[r] = 0;   // k2_rank accumulates with atomics
        cvs[threadIdx.x >> 2] = (u32)bestc | (valid ? 256u : 0u);
    }
    // kvb zeroed by plain same-value stores from every block (k2 accumulates after)
    if (threadIdx.x == 0) kvb[blockIdx.x >> 6] = 0;
    __syncthreads();
    if (threadIdx.x < 64) {
        // wave 0: 64 ballots -> per-class 64-bit validity mask for this group
        u32 s = cvs[threadIdx.x];
        int cls = (int)(s & 255u);
        bool v = (s & 256u) != 0u;
        u64 mym = 0;
        for (int c = 0; c < 64; ++c) {
            u64 m = __ballot(v && (cls == c));
            if (threadIdx.x == c) mym = m;
        }
        int b = blockIdx.x >> 6, g = blockIdx.x & 63;
        // class-major layout: k3 lane g reads contiguous 512B per (b,class)
        clsmask[(((size_t)(b << 6) + (size_t)threadIdx.x) << 6) + g] = mym;
    }
}

// ---------------- k2: rank_i = #{j in batch: key_j > key_i}. E=4 chunk reuse:
// each thread ranks FOUR elements against the same staged 256-key chunk, so
// each broadcast ds_read_b128 feeds 8 compares (per-CU DS instructions halved
// vs E=2; VALU unchanged ~1.7 us; DS ~1.7 us => balanced). Grid 256 blocks =
// 16 ksegs x 4 esegs x 4 batches = exactly 1 block/CU (8 XCDs x 32). kseg
// count unchanged at 16 => atomic partial count unchanged (262144). LDS reads
// are wave-uniform => broadcast, conflict-free. kseg==0 blocks also accumulate
// kvb[b] = #valid (keys >= 2^43).
__global__ __launch_bounds__(256) void k2_rank(const u64* __restrict__ key64,
                                               int* __restrict__ rank,
                                               int* __restrict__ kvb) {
    __shared__ u64 sk[256];      // 2 KB: this block's 256-key chunk
    int bid = blockIdx.x;
    int kseg = bid & 15;         // which 256-key chunk we scan
    int eseg = (bid >> 4) & 3;   // which 1024 elements we own (4 per thread)
    int b    = bid >> 6;
    int tid = threadIdx.x;
    const u64* kb = key64 + ((size_t)b << 12);
    sk[tid] = kb[(kseg << 8) + tid];
    __syncthreads();
    int i0 = (eseg << 10) + tid;       // elements i0, i0+256, i0+512, i0+768
    u64 my0 = kb[i0];
    u64 my1 = kb[i0 + 256];
    u64 my2 = kb[i0 + 512];
    u64 my3 = kb[i0 + 768];
    int r0 = 0, r1 = 0, r2 = 0, r3 = 0;
    const ulonglong2* s2 = (const ulonglong2*)sk;   // b128 reads, 2 keys each
#pragma unroll 8
    for (int q = 0; q < 128; ++q) {
        ulonglong2 v = s2[q];
        r0 += (int)(v.x > my0) + (int)(v.y > my0);
        r1 += (int)(v.x > my1) + (int)(v.y > my1);
        r2 += (int)(v.x > my2) + (int)(v.y > my2);
        r3 += (int)(v.x > my3) + (int)(v.y > my3);
    }
    int* rb = rank + (b << 12);
    atomicAdd(&rb[i0], r0);
    atomicAdd(&rb[i0 + 256], r1);
    atomicAdd(&rb[i0 + 512], r2);
    atomicAdd(&rb[i0 + 768], r3);
    if (kseg == 0) {
        u64 bal0 = __ballot(my0 >= (1ull << 43));   // valid <=> score field top bit
        u64 bal1 = __ballot(my1 >= (1ull << 43));
        u64 bal2 = __ballot(my2 >= (1ull << 43));
        u64 bal3 = __ballot(my3 >= (1ull << 43));
        if ((tid & 63) == 0)
            atomicAdd(&kvb[b], (int)(__popcll(bal0) + __popcll(bal1)
                                     + __popcll(bal2) + __popcll(bal3)));
    }
}

// ---------------- k3: one wave per (batch,class). Cross-class IoU is exactly 0
// (offset >= 4096 > extent), so global greedy NMS == independent per-class greedy
// in global-rank order. Output row of element e IS rank[e]. Invalid rows are the
// contiguous tail [kv,4096) (valid keys all > invalid keys) -> closed-form zero
// sweep; valid element ids come from k1's ballot masks (no full scan). Phase A
// issues ALL per-element gathers (rank, box, key) concurrently -- one latency
// round -- and stores clipped box + conf into LDS indexed by rank; everything
// downstream (IoU, emit) runs from LDS. Together with the other 63 class-blocks
// of this batch, coverage of d_out is complete (poisoned each call).
__global__ __launch_bounds__(64) void k3_nms(const float* __restrict__ boxes,
                                             const u64* __restrict__ key64,
                                             const int* __restrict__ rank,
                                             const u64* __restrict__ clsmask,
                                             const int* __restrict__ kvb,
                                             float* __restrict__ out) {
    __shared__ u32 bitset[128];     // 4096 bits over sorted positions (ranks)
    __shared__ float4 pbox[NN];     // 64 KB: rank -> clipped box (owned ranks only)
    __shared__ float  pcf[NN];      // 16 KB: rank -> conf
    __shared__ u16 lpos[MAXB];      //  2 KB: compact index -> rank
    __shared__ float4 lbox[MAXB];   // 16 KB: compact index -> offset box
    __shared__ float larea[128];    // fast-path broadcast areas
    // ~99 KB LDS total: irrelevant to occupancy (256 one-wave blocks on 256 CUs).
    const int lane = threadIdx.x;
    const int b = blockIdx.x >> 6;
    const int myc = blockIdx.x & 63;
    const int base = b << 12;       // element base == output row base
    const float off = (float)myc * MAX_WH;   // exact (c * 2^12)
    const float4* braw = (const float4*)boxes + base;

    // --- tail sweep: invalid ranks are exactly [kv, 4096); the 64 class-blocks
    // of this batch stripe them mod 64. lane t covers p = kv+myc+64t (<=64 rows).
    const int kv = kvb[b];
    {
        int p = kv + myc + (lane << 6);
        if (p < NN) zero_row(out, base + p);
    }

    bitset[2 * lane] = 0;
    bitset[2 * lane + 1] = 0;
    __syncthreads();

    // --- Phase A: ingest this (batch,class) validity mask column; gather rank,
    // raw box, and key for each owned element CONCURRENTLY (same index e, no
    // dependence); clip + conf immediately; store by rank into LDS.
    {
        u64 m = clsmask[(((size_t)(b << 6) + (size_t)myc) << 6) + lane];
        while (m) {
            int bit = (int)__builtin_ctzll(m); m &= m - 1;
            int e = (lane << 6) + bit;
            int rk = rank[base + e];
            float4 bcl = clip_box(braw[e]);
            float cf = conf_of(key64[base + e]);
            atomicOr(&bitset[rk >> 5], 1u << (rk & 31));
            pbox[rk] = bcl;
            pcf[rk] = cf;
        }
    }
    __syncthreads();

    // --- Phase B: compact ranks ascending (lane owns ranks [64*lane, 64*lane+64)) ---
    u64 w = ((u64)bitset[2 * lane + 1] << 32) | (u64)bitset[2 * lane];
    int cnt = (int)__popcll(w);
    int incl = cnt;
#pragma unroll
    for (int d2 = 1; d2 < 64; d2 <<= 1) {
        int t2 = __shfl_up(incl, d2);
        if (lane >= d2) incl += t2;
    }
    int kk = __shfl(incl, 63);
    {
        int d = incl - cnt;
        u64 t = w;
        while (t) {
            int b2 = (int)__builtin_ctzll(t); t &= t - 1;
            int p = (lane << 6) + b2;
            if (d < MAXB) lpos[d] = (u16)p; else zero_row(out, base + p);
            d++;
        }
    }
    if (kk > MAXB) kk = MAXB;
    if (kk == 0) return;
    __syncthreads();

    if (kk <= 128) {
        // --- fast path: k x k IoU bit-matrix in registers; operand broadcast via
        // wave-uniform LDS reads (lbox/larea). All data already in LDS.
        const int j0 = lane, j1 = 64 + lane;
        bool in0 = j0 < kk, in1 = j1 < kk;
        float4 bcl0 = {0, 0, 0, 0}, bcl1 = {0, 0, 0, 0};   // clipped (for emit)
        float4 box0 = {0, 0, 0, 0}, box1 = {0, 0, 0, 0};   // offset (for IoU)
        float a0 = 0.0f, a1 = 0.0f, cf0 = 0.0f, cf1 = 0.0f;
        int p0 = 0, p1 = 0;
        if (in0) {
            p0 = lpos[j0];
            bcl0 = pbox[p0]; cf0 = pcf[p0];
            box0.x = bcl0.x + off; box0.y = bcl0.y + off; box0.z = bcl0.z + off; box0.w = bcl0.w + off;
            a0 = (box0.z - box0.x) * (box0.w - box0.y);   // ref: area on offset boxes
            lbox[j0] = box0; larea[j0] = a0;
        }
        if (in1) {
            p1 = lpos[j1];
            bcl1 = pbox[p1]; cf1 = pcf[p1];
            box1.x = bcl1.x + off; box1.y = bcl1.y + off; box1.z = bcl1.z + off; box1.w = bcl1.w + off;
            a1 = (box1.z - box1.x) * (box1.w - box1.y);
            lbox[j1] = box1; larea[j1] = a1;
        }
        __syncthreads();
        u64 r00 = 0, r10 = 0, r11 = 0;   // bit i of column j: iou(i,j) > thr
        if (kk <= 64) {
            for (int i = 0; i < kk; ++i) {   // independent iterations -> pipelined
                float4 bi = lbox[i];
                float ai = larea[i];
                bool s0 = in0 && (j0 > i) && iou_gt(bi, ai, box0, a0);
                r00 |= ((u64)s0) << i;
            }
        } else {
            for (int i = 0; i < kk; ++i) {
                float4 bi = lbox[i];
                float ai = larea[i];
                bool s0 = in0 && (j0 > i) && iou_gt(bi, ai, box0, a0);
                bool s1 = in1 && (j1 > i) && iou_gt(bi, ai, box1, a1);
                if (i < 64) { r00 |= ((u64)s0) << i; r10 |= ((u64)s1) << i; }
                else        { r11 |= ((u64)s1) << (i - 64); }
            }
        }
        // greedy scan, ~15 register cycles per step (validated prior sessions, absmax 0)
        u32 sup0 = 0, sup1 = 0;
        int kc = kk < 64 ? kk : 64;
        for (int i = 0; i < kc; ++i) {
            u64 f = __ballot(sup0 != 0);
            u32 km = ((f >> i) & 1ull) ? 0u : ~0u;   // keep_i mask
            sup0 |= km & (u32)((r00 >> i) & 1ull);
            sup1 |= km & (u32)((r10 >> i) & 1ull);
        }
        for (int i = 64; i < kk; ++i) {
            u64 f = __ballot(sup1 != 0);
            u32 km = ((f >> (i - 64)) & 1ull) ? 0u : ~0u;
            sup1 |= km & (u32)((r11 >> (i - 64)) & 1ull);
        }
        // emit (register/LDS only)
        if (in0) {
            if (!sup0) emit_row(out, base + p0, bcl0, cf0, (float)myc);
            else zero_row(out, base + p0);
        }
        if (in1) {
            if (!sup1) emit_row(out, base + p1, bcl1, cf1, (float)myc);
            else zero_row(out, base + p1);
        }
    } else {
        // --- general fallback (never taken on bench data; correctness net) ---
        for (int m = lane; m < kk; m += 64) {
            float4 bc4 = pbox[lpos[m]];
            float4 ob; ob.x = bc4.x + off; ob.y = bc4.y + off; ob.z = bc4.z + off; ob.w = bc4.w + off;
            lbox[m] = ob;
        }
        __syncthreads();
        u64 supw = 0;   // lane w owns suppression bits [64w, 64w+64)
        for (int i = 0; i < kk; ++i) {
            u64 wd = __shfl(supw, i >> 6);
            if (((wd >> (i & 63)) & 1ull) == 0ull) {
                float4 bi = lbox[i];
                float ai = (bi.z - bi.x) * (bi.w - bi.y);
                for (int jb = (i + 1) & ~63; jb < kk; jb += 64) {
                    int j = jb + lane;
                    bool s = false;
                    if (j > i && j < kk) {
                        float4 bj = lbox[j];
                        float aj = (bj.z - bj.x) * (bj.w - bj.y);
                        s = iou_gt(bi, ai, bj, aj);
                    }
                    u64 m2 = __ballot(s);
                    if (lane == (jb >> 6)) supw |= m2;
                }
            }
        }
        for (int t2 = 0; t2 * 64 < kk; ++t2) {
            int m = t2 * 64 + lane;
            u64 wd = __shfl(supw, t2);
            if (m < kk) {
                int p = lpos[m];
                if (((wd >> lane) & 1ull) == 0ull)
                    emit_row(out, base + p, pbox[p], pcf[p], (float)myc);
                else zero_row(out, base + p);
            }
        }
    }
}

extern "C" void kernel_launch(void* const* d_in, const int* in_sizes, int n_in,
                              void* d_out, int out_size, void* d_ws, size_t ws_size,
                              hipStream_t stream) {
    const float* boxes      = (const float*)d_in[0];   // [B,N,4]
    const float* box_scores = (const float*)d_in[1];   // [B,N]
    const float* cls_preds  = (const float*)d_in[2];   // [B,N,C]

    char* ws = (char*)d_ws;
    size_t off = 0;
    u64* key64   = (u64*)(ws + off); off += (size_t)BN * 8;           // 128 KB
    int* rank    = (int*)(ws + off); off += (size_t)BN * 4;           //  64 KB
    u64* clsmask = (u64*)(ws + off); off += (size_t)BB * 64 * CC * 8; // 128 KB
    int* kvb     = (int*)(ws + off); off += (size_t)BB * 4;           //  16 B
    // total 320 KB + 16 B -- well under the 576 KB proven-safe footprint; no memset.

    k1_score<<<BN / 64, 256, 0, stream>>>(boxes, box_scores, cls_preds,
                                          key64, rank, clsmask, kvb);
    k2_rank<<<BB * 64, 256, 0, stream>>>(key64, rank, kvb);
    k3_nms<<<BB * CC, 64, 0, stream>>>(boxes, key64, rank, clsmask, kvb, (float*)d_out);
}

// Round 8
// 96.798 us; speedup vs baseline: 1.0170x; 1.0170x over previous
//
#include <hip/hip_runtime.h>
#include <stdint.h>

// Bitwise reproducibility vs the numpy reference: forbid a*b+c fusion so every
// mul/add rounds exactly like the ref (keep-decision booleans must not flip).
#pragma clang fp contract(off)

typedef unsigned long long u64;
typedef unsigned int u32;
typedef unsigned short u16;

namespace {
constexpr int BB = 4;
constexpr int NN = 4096;
constexpr int CC = 64;
constexpr int BN = BB * NN;
constexpr float TARGET = 560.0f;
constexpr float MIN_BOX = 5.0f;
constexpr float IOU_THR = 0.2f;
constexpr float CONF_THR = 0.001f;
constexpr float BOX_CONF_THR = 0.01f;
constexpr float MAX_WH = 4096.0f;
constexpr int MAXB = 1024;   // k3 compact-list cap; data has ~64 +/- 8 per class
}

__device__ __forceinline__ void zero_row(float* __restrict__ out, int p) {
    float2* o2 = (float2*)(out + (size_t)p * 6);   // p*24B is 8B-aligned
    float2 z; z.x = 0.0f; z.y = 0.0f;
    o2[0] = z; o2[1] = z; o2[2] = z;
}

__device__ __forceinline__ void emit_row(float* __restrict__ out, int p,
                                         float4 bc, float cf, float cls) {
    float2* o2 = (float2*)(out + (size_t)p * 6);
    float2 aa; aa.x = bc.x; aa.y = bc.y;
    float2 cc; cc.x = bc.z; cc.y = bc.w;
    float2 ee; ee.x = cf;   ee.y = cls;
    o2[0] = aa; o2[1] = cc; o2[2] = ee;
}

// clip to [0,TARGET] with the ref's exact op order
__device__ __forceinline__ float4 clip_box(float4 bx) {
    float4 r;
    r.x = fminf(fmaxf(bx.x, 0.0f), TARGET);
    r.y = fminf(fmaxf(bx.y, 0.0f), TARGET);
    r.z = fminf(fmaxf(bx.z, 0.0f), TARGET);
    r.w = fminf(fmaxf(bx.w, 0.0f), TARGET);
    return r;
}

// conf of a VALID element is exactly recoverable from its key's score field:
// valid => sk = best >= 0 => fb sign clear => mm = fb | 0x80000000.
__device__ __forceinline__ float conf_of(u64 key) {
    return __uint_as_float(((u32)(key >> 12)) & 0x7FFFFFFFu);
}

// IoU(i,j) > thr with the ref's exact op order (offset boxes, precomputed areas,
// inter/(ai+aj-inter+1e-9) with IEEE division).
__device__ __forceinline__ bool iou_gt(float4 bi, float ai, float4 bj, float aj) {
    float ltx = fmaxf(bi.x, bj.x);
    float lty = fmaxf(bi.y, bj.y);
    float rbx = fminf(bi.z, bj.z);
    float rby = fminf(bi.w, bj.w);
    float ww = fmaxf(rbx - ltx, 0.0f);
    float hh = fmaxf(rby - lty, 0.0f);
    float inter = ww * hh;
    float iou = inter / (ai + aj - inter + 1e-9f);
    return iou > IOU_THR;
}

// ---------------- k1: conf=max_c(cls*score), argmax, valid, 44-bit key
// (sign-mapped score <<12 | reversed idx => embedded index tie-break, 1 u64
// compare in k2), zero the rank buffer, and build per-(batch,class) validity
// bitmasks via wave ballots (no atomics, no pre-zeroed state). Valid keys
// (>= 2^43) all exceed invalid keys => valid ranks are exactly [0,kv) and
// invalid rows are exactly [kv,4096) -- k3 exploits both. 4 lanes per row;
// block = 64 rows = one mask group. Boxes are NOT staged: k3 re-clips raw input.
__global__ __launch_bounds__(256) void k1_score(const float* __restrict__ boxes,
                                                const float* __restrict__ box_scores,
                                                const float* __restrict__ cls_preds,
                                                u64* __restrict__ key64,
                                                int* __restrict__ rank,
                                                u64* __restrict__ clsmask,
                                                int* __restrict__ kvb) {
    __shared__ u32 cvs[64];                           // per-row packed (cls | valid<<8)
    int r = (blockIdx.x << 6) + (threadIdx.x >> 2);   // 64 rows/block
    int sub = threadIdx.x & 3;
    float bs = box_scores[r];
    const float4* cp = (const float4*)(cls_preds + ((size_t)r << 6) + (sub << 4));
    float best = -1.0f;   // products >= 0, so first element always beats init
    int bestc = sub << 4;
#pragma unroll
    for (int q = 0; q < 4; ++q) {
        float4 v = cp[q];
        float p0 = v.x * bs, p1 = v.y * bs, p2 = v.z * bs, p3 = v.w * bs;
        int cb = (sub << 4) + (q << 2);
        // strict > preserves numpy first-occurrence argmax within a lane
        if (p0 > best) { best = p0; bestc = cb + 0; }
        if (p1 > best) { best = p1; bestc = cb + 1; }
        if (p2 > best) { best = p2; bestc = cb + 2; }
        if (p3 > best) { best = p3; bestc = cb + 3; }
    }
    // quad merge; exact-tie -> smaller class index == first occurrence
#pragma unroll
    for (int d2 = 1; d2 < 4; d2 <<= 1) {
        float ob = __shfl_xor(best, d2);
        int oc = __shfl_xor(bestc, d2);
        if (ob > best || (ob == best && oc < bestc)) { best = ob; bestc = oc; }
    }
    if (sub == 0) {
        float4 bc4 = clip_box(((const float4*)boxes)[r]);
        float w = bc4.z - bc4.x, h = bc4.w - bc4.y;
        bool valid = (bs > BOX_CONF_THR) && (w > MIN_BOX) && (h > MIN_BOX) && (best > CONF_THR);
        float sk = valid ? best : -1.0f;
        // monotonic float->uint map; unique key: ties rank smaller original index
        // first => stable descending sort by score.
        unsigned fb = __float_as_uint(sk);
        unsigned mm = (fb & 0x80000000u) ? ~fb : (fb | 0x80000000u);
        int i = r & (NN - 1);
        key64[r] = ((u64)mm << 12) | (u64)(NN - 1 - i);
        rank[r] = 0;   // k2_rank accumulates with atomics
        cvs[threadIdx.x >> 2] = (u32)bestc | (valid ? 256u : 0u);
    }
    // kvb zeroed by plain same-value stores from every block (k2 accumulates after)
    if (threadIdx.x == 0) kvb[blockIdx.x >> 6] = 0;
    __syncthreads();
    if (threadIdx.x < 64) {
        // wave 0: 64 ballots -> per-class 64-bit validity mask for this group
        u32 s = cvs[threadIdx.x];
        int cls = (int)(s & 255u);
        bool v = (s & 256u) != 0u;
        u64 mym = 0;
        for (int c = 0; c < 64; ++c) {
            u64 m = __ballot(v && (cls == c));
            if (threadIdx.x == c) mym = m;
        }
        int b = blockIdx.x >> 6, g = blockIdx.x & 63;
        // class-major layout: k3 lane g reads contiguous 512B per (b,class)
        clsmask[(((size_t)(b << 6) + (size_t)threadIdx.x) << 6) + g] = mym;
    }
}

// ---------------- k2: rank_i = #{j in batch: key_j > key_i}. E=2 chunk reuse:
// each thread ranks TWO elements against the same staged 256-key chunk, so each
// broadcast ds_read_b128 feeds 4 compares (halves per-CU DS instructions vs the
// 1-element form; VALU unchanged at ~1.7 us floor). Grid 512 = 16 ksegs x
// 8 esegs x 4 batches = 2 blocks/CU = 8 waves/CU (E=4's 1 block/CU regressed:
// latency-hiding TLP loss exceeded the DS saving -- r7 measured). Exact int
// atomic accumulation (16 partials/element). LDS reads are wave-uniform =>
// broadcast, conflict-free. kseg==0 blocks also accumulate kvb[b] = #valid.
__global__ __launch_bounds__(256) void k2_rank(const u64* __restrict__ key64,
                                               int* __restrict__ rank,
                                               int* __restrict__ kvb) {
    __shared__ u64 sk[256];      // 2 KB: this block's 256-key chunk
    int bid = blockIdx.x;
    int kseg = bid & 15;         // which 256-key chunk we scan
    int eseg = (bid >> 4) & 7;   // which 512 elements we own (2 per thread)
    int b    = bid >> 7;
    int tid = threadIdx.x;
    const u64* kb = key64 + ((size_t)b << 12);
    sk[tid] = kb[(kseg << 8) + tid];
    __syncthreads();
    int i0 = (eseg << 9) + tid;        // elements [eseg*512, eseg*512+256)
    int i1 = i0 + 256;                 // and      [eseg*512+256, eseg*512+512)
    u64 my0 = kb[i0];
    u64 my1 = kb[i1];
    int r0 = 0, r1 = 0;
    const ulonglong2* s2 = (const ulonglong2*)sk;   // b128 reads, 2 keys each
#pragma unroll 16
    for (int q = 0; q < 128; ++q) {
        ulonglong2 v = s2[q];
        r0 += (int)(v.x > my0) + (int)(v.y > my0);
        r1 += (int)(v.x > my1) + (int)(v.y > my1);
    }
    atomicAdd(&rank[(b << 12) + i0], r0);
    atomicAdd(&rank[(b << 12) + i1], r1);
    if (kseg == 0) {
        u64 bal0 = __ballot(my0 >= (1ull << 43));   // valid <=> score field top bit
        u64 bal1 = __ballot(my1 >= (1ull << 43));
        if ((tid & 63) == 0)
            atomicAdd(&kvb[b], (int)(__popcll(bal0) + __popcll(bal1)));
    }
}

// ---------------- k3: one wave per (batch,class). Cross-class IoU is exactly 0
// (offset >= 4096 > extent), so global greedy NMS == independent per-class greedy
// in global-rank order. Output row of element e IS rank[e]. Invalid rows are the
// contiguous tail [kv,4096) (valid keys all > invalid keys) -> closed-form zero
// sweep; valid element ids come from k1's ballot masks (no full scan). Phase A
// issues ALL per-element gathers (rank, box, key) concurrently -- one latency
// round -- and stores clipped box + conf into LDS indexed by rank; everything
// downstream (IoU, emit) runs from LDS. Together with the other 63 class-blocks
// of this batch, coverage of d_out is complete (poisoned each call).
__global__ __launch_bounds__(64) void k3_nms(const float* __restrict__ boxes,
                                             const u64* __restrict__ key64,
                                             const int* __restrict__ rank,
                                             const u64* __restrict__ clsmask,
                                             const int* __restrict__ kvb,
                                             float* __restrict__ out) {
    __shared__ u32 bitset[128];     // 4096 bits over sorted positions (ranks)
    __shared__ float4 pbox[NN];     // 64 KB: rank -> clipped box (owned ranks only)
    __shared__ float  pcf[NN];      // 16 KB: rank -> conf
    __shared__ u16 lpos[MAXB];      //  2 KB: compact index -> rank
    __shared__ float4 lbox[MAXB];   // 16 KB: compact index -> offset box
    __shared__ float larea[128];    // fast-path broadcast areas
    // ~99 KB LDS total: irrelevant to occupancy (256 one-wave blocks on 256 CUs).
    const int lane = threadIdx.x;
    const int b = blockIdx.x >> 6;
    const int myc = blockIdx.x & 63;
    const int base = b << 12;       // element base == output row base
    const float off = (float)myc * MAX_WH;   // exact (c * 2^12)
    const float4* braw = (const float4*)boxes + base;

    // --- tail sweep: invalid ranks are exactly [kv, 4096); the 64 class-blocks
    // of this batch stripe them mod 64. lane t covers p = kv+myc+64t (<=64 rows).
    const int kv = kvb[b];
    {
        int p = kv + myc + (lane << 6);
        if (p < NN) zero_row(out, base + p);
    }

    bitset[2 * lane] = 0;
    bitset[2 * lane + 1] = 0;
    __syncthreads();

    // --- Phase A: ingest this (batch,class) validity mask column; gather rank,
    // raw box, and key for each owned element CONCURRENTLY (same index e, no
    // dependence); clip + conf immediately; store by rank into LDS.
    {
        u64 m = clsmask[(((size_t)(b << 6) + (size_t)myc) << 6) + lane];
        while (m) {
            int bit = (int)__builtin_ctzll(m); m &= m - 1;
            int e = (lane << 6) + bit;
            int rk = rank[base + e];
            float4 bcl = clip_box(braw[e]);
            float cf = conf_of(key64[base + e]);
            atomicOr(&bitset[rk >> 5], 1u << (rk & 31));
            pbox[rk] = bcl;
            pcf[rk] = cf;
        }
    }
    __syncthreads();

    // --- Phase B: compact ranks ascending (lane owns ranks [64*lane, 64*lane+64)) ---
    u64 w = ((u64)bitset[2 * lane + 1] << 32) | (u64)bitset[2 * lane];
    int cnt = (int)__popcll(w);
    int incl = cnt;
#pragma unroll
    for (int d2 = 1; d2 < 64; d2 <<= 1) {
        int t2 = __shfl_up(incl, d2);
        if (lane >= d2) incl += t2;
    }
    int kk = __shfl(incl, 63);
    {
        int d = incl - cnt;
        u64 t = w;
        while (t) {
            int b2 = (int)__builtin_ctzll(t); t &= t - 1;
            int p = (lane << 6) + b2;
            if (d < MAXB) lpos[d] = (u16)p; else zero_row(out, base + p);
            d++;
        }
    }
    if (kk > MAXB) kk = MAXB;
    if (kk == 0) return;
    __syncthreads();

    if (kk <= 128) {
        // --- fast path: k x k IoU bit-matrix in registers; operand broadcast via
        // wave-uniform LDS reads (lbox/larea). All data already in LDS.
        const int j0 = lane, j1 = 64 + lane;
        bool in0 = j0 < kk, in1 = j1 < kk;
        float4 bcl0 = {0, 0, 0, 0}, bcl1 = {0, 0, 0, 0};   // clipped (for emit)
        float4 box0 = {0, 0, 0, 0}, box1 = {0, 0, 0, 0};   // offset (for IoU)
        float a0 = 0.0f, a1 = 0.0f, cf0 = 0.0f, cf1 = 0.0f;
        int p0 = 0, p1 = 0;
        if (in0) {
            p0 = lpos[j0];
            bcl0 = pbox[p0]; cf0 = pcf[p0];
            box0.x = bcl0.x + off; box0.y = bcl0.y + off; box0.z = bcl0.z + off; box0.w = bcl0.w + off;
            a0 = (box0.z - box0.x) * (box0.w - box0.y);   // ref: area on offset boxes
            lbox[j0] = box0; larea[j0] = a0;
        }
        if (in1) {
            p1 = lpos[j1];
            bcl1 = pbox[p1]; cf1 = pcf[p1];
            box1.x = bcl1.x + off; box1.y = bcl1.y + off; box1.z = bcl1.z + off; box1.w = bcl1.w + off;
            a1 = (box1.z - box1.x) * (box1.w - box1.y);
            lbox[j1] = box1; larea[j1] = a1;
        }
        __syncthreads();
        u64 r00 = 0, r10 = 0, r11 = 0;   // bit i of column j: iou(i,j) > thr
        if (kk <= 64) {
            for (int i = 0; i < kk; ++i) {   // independent iterations -> pipelined
                float4 bi = lbox[i];
                float ai = larea[i];
                bool s0 = in0 && (j0 > i) && iou_gt(bi, ai, box0, a0);
                r00 |= ((u64)s0) << i;
            }
        } else {
            for (int i = 0; i < kk; ++i) {
                float4 bi = lbox[i];
                float ai = larea[i];
                bool s0 = in0 && (j0 > i) && iou_gt(bi, ai, box0, a0);
                bool s1 = in1 && (j1 > i) && iou_gt(bi, ai, box1, a1);
                if (i < 64) { r00 |= ((u64)s0) << i; r10 |= ((u64)s1) << i; }
                else        { r11 |= ((u64)s1) << (i - 64); }
            }
        }
        // greedy scan, ~15 register cycles per step (validated prior sessions, absmax 0)
        u32 sup0 = 0, sup1 = 0;
        int kc = kk < 64 ? kk : 64;
        for (int i = 0; i < kc; ++i) {
            u64 f = __ballot(sup0 != 0);
            u32 km = ((f >> i) & 1ull) ? 0u : ~0u;   // keep_i mask
            sup0 |= km & (u32)((r00 >> i) & 1ull);
            sup1 |= km & (u32)((r10 >> i) & 1ull);
        }
        for (int i = 64; i < kk; ++i) {
            u64 f = __ballot(sup1 != 0);
            u32 km = ((f >> (i - 64)) & 1ull) ? 0u : ~0u;
            sup1 |= km & (u32)((r11 >> (i - 64)) & 1ull);
        }
        // emit (register/LDS only)
        if (in0) {
            if (!sup0) emit_row(out, base + p0, bcl0, cf0, (float)myc);
            else zero_row(out, base + p0);
        }
        if (in1) {
            if (!sup1) emit_row(out, base + p1, bcl1, cf1, (float)myc);
            else zero_row(out, base + p1);
        }
    } else {
        // --- general fallback (never taken on bench data; correctness net) ---
        for (int m = lane; m < kk; m += 64) {
            float4 bc4 = pbox[lpos[m]];
            float4 ob; ob.x = bc4.x + off; ob.y = bc4.y + off; ob.z = bc4.z + off; ob.w = bc4.w + off;
            lbox[m] = ob;
        }
        __syncthreads();
        u64 supw = 0;   // lane w owns suppression bits [64w, 64w+64)
        for (int i = 0; i < kk; ++i) {
            u64 wd = __shfl(supw, i >> 6);
            if (((wd >> (i & 63)) & 1ull) == 0ull) {
                float4 bi = lbox[i];
                float ai = (bi.z - bi.x) * (bi.w - bi.y);
                for (int jb = (i + 1) & ~63; jb < kk; jb += 64) {
                    int j = jb + lane;
                    bool s = false;
                    if (j > i && j < kk) {
                        float4 bj = lbox[j];
                        float aj = (bj.z - bj.x) * (bj.w - bj.y);
                        s = iou_gt(bi, ai, bj, aj);
                    }
                    u64 m2 = __ballot(s);
                    if (lane == (jb >> 6)) supw |= m2;
                }
            }
        }
        for (int t2 = 0; t2 * 64 < kk; ++t2) {
            int m = t2 * 64 + lane;
            u64 wd = __shfl(supw, t2);
            if (m < kk) {
                int p = lpos[m];
                if (((wd >> lane) & 1ull) == 0ull)
                    emit_row(out, base + p, pbox[p], pcf[p], (float)myc);
                else zero_row(out, base + p);
            }
        }
    }
}

extern "C" void kernel_launch(void* const* d_in, const int* in_sizes, int n_in,
                              void* d_out, int out_size, void* d_ws, size_t ws_size,
                              hipStream_t stream) {
    const float* boxes      = (const float*)d_in[0];   // [B,N,4]
    const float* box_scores = (const float*)d_in[1];   // [B,N]
    const float* cls_preds  = (const float*)d_in[2];   // [B,N,C]

    char* ws = (char*)d_ws;
    size_t off = 0;
    u64* key64   = (u64*)(ws + off); off += (size_t)BN * 8;           // 128 KB
    int* rank    = (int*)(ws + off); off += (size_t)BN * 4;           //  64 KB
    u64* clsmask = (u64*)(ws + off); off += (size_t)BB * 64 * CC * 8; // 128 KB
    int* kvb     = (int*)(ws + off); off += (size_t)BB * 4;           //  16 B
    // total 320 KB + 16 B -- well under the 576 KB proven-safe footprint; no memset.

    k1_score<<<BN / 64, 256, 0, stream>>>(boxes, box_scores, cls_preds,
                                          key64, rank, clsmask, kvb);
    k2_rank<<<BB * 128, 256, 0, stream>>>(key64, rank, kvb);
    k3_nms<<<BB * CC, 64, 0, stream>>>(boxes, key64, rank, clsmask, kvb, (float*)d_out);
}